// Round 4
// baseline (290.559 us; speedup 1.0000x reference)
//
#include <hip/hip_runtime.h>
#include <hip/hip_bf16.h>
#include <stdint.h>

// B=8, C=256, H=W=64 (N=4096), T=512
// out0 = F_s + (softmax(Fs_t @ Ft^T / sqrt(T)) @ Ft) in [B][C][N] layout, fp32
// out1 = P^T @ Fs_t   [B][T][C] fp32

typedef __attribute__((ext_vector_type(8))) short short8v;   // 8 bf16
typedef __attribute__((ext_vector_type(4))) float float4v;

#define MFMA16(a, b, c) __builtin_amdgcn_mfma_f32_16x16x32_bf16(a, b, c, 0, 0, 0)
#define SCALE 0.04419417382415922f  // 1/sqrt(512)

static __device__ __forceinline__ unsigned short f2bf(float f) {
  union { float f; uint32_t u; } v; v.f = f;
  uint32_t r = v.u + 0x7fffu + ((v.u >> 16) & 1u);   // RNE
  return (unsigned short)(r >> 16);
}

// ---------- cast + transpose (unchanged from round 2) ----------
__global__ __launch_bounds__(256) void k_cast_transpose(
    const float* __restrict__ src, unsigned short* __restrict__ dstC,
    unsigned short* __restrict__ dstT, int R, int Cd) {
  __shared__ unsigned short tile[32][33];
  const size_t zoff = (size_t)blockIdx.z * R * Cd;
  const float* s = src + zoff;
  unsigned short* dc = dstC + zoff;
  unsigned short* dt = dstT + zoff;
  const int c0 = blockIdx.x * 32, r0 = blockIdx.y * 32;
  const int tid = threadIdx.x;
  const int r = tid >> 3, c4 = (tid & 7) * 4;

  float4 v = *(const float4*)&s[(size_t)(r0 + r) * Cd + c0 + c4];
  ushort4 bq;
  bq.x = f2bf(v.x); bq.y = f2bf(v.y); bq.z = f2bf(v.z); bq.w = f2bf(v.w);
  *(ushort4*)&dc[(size_t)(r0 + r) * Cd + c0 + c4] = bq;
  tile[r][c4 + 0] = bq.x; tile[r][c4 + 1] = bq.y;
  tile[r][c4 + 2] = bq.z; tile[r][c4 + 3] = bq.w;
  __syncthreads();
  ushort4 o;
  o.x = tile[c4 + 0][r]; o.y = tile[c4 + 1][r];
  o.z = tile[c4 + 2][r]; o.w = tile[c4 + 3][r];
  *(ushort4*)&dt[(size_t)(c0 + r) * R + r0 + c4] = o;
}

// ---------- fused attention: QBLK=64, 8 waves, T14 prefetch, fat stages ----------
// grid (64 n-blocks, 8 batches), 512 threads.
// LDS: [0,36864) stage [256][72] bf16 (K then VT chunks)
//      [36864,103424) Plds [64][520] bf16  (overlaid: red f32[2][8][32] early; Olds f32[64][260] late)
__global__ __launch_bounds__(512) void k_attn(
    const unsigned short* __restrict__ Qg, const unsigned short* __restrict__ Kg,
    const unsigned short* __restrict__ VTg, const float* __restrict__ Fs,
    float* __restrict__ out0, unsigned short* __restrict__ PTg) {
  __shared__ char smem[103424];
  unsigned short* stageU = (unsigned short*)smem;          // [256][72]
  unsigned short* Plds = (unsigned short*)(smem + 36864);  // [64][520]
  float* red = (float*)(smem + 36864);                     // [2][8][32] overlay
  float* Olds = (float*)(smem + 36864);                    // [64][260] overlay

  const int tid = threadIdx.x;
  const int wave = tid >> 6, lane = tid & 63;
  const int l16 = lane & 15, lhi = lane >> 4;
  const int wq = wave >> 2, wt = wave & 3;   // q-half, t/c-quarter
  const int b = blockIdx.y, n0 = blockIdx.x * 64;

  const unsigned short* Qb = Qg + (size_t)b * 4096 * 256;
  const unsigned short* Kb = Kg + (size_t)b * 512 * 256;
  const unsigned short* VTb = VTg + (size_t)b * 256 * 512;

  // staging decomposition: 2048 int4 chunks, 4 per thread
  const int sr0 = tid >> 3;                 // base row, +64 per iter via idx
  const int sc0 = (tid & 7) * 8;

  // ---- Q fragments in registers ----
  short8v a[2][8];
#pragma unroll
  for (int mi = 0; mi < 2; mi++)
#pragma unroll
    for (int kk = 0; kk < 8; kk++)
      a[mi][kk] = *(const short8v*)(Qb + (size_t)(n0 + wq * 32 + mi * 16 + l16) * 256 + kk * 32 + lhi * 8);

  float4v acc[2][8];
#pragma unroll
  for (int mi = 0; mi < 2; mi++)
#pragma unroll
    for (int tj = 0; tj < 8; tj++) acc[mi][tj] = (float4v)0.f;

  int4 sreg[4];

#define LOADK(s_) do { \
    const int th_ = (s_) >> 2, kk_ = (s_) & 3; \
    _Pragma("unroll") \
    for (int i = 0; i < 4; i++) { \
      int r_ = sr0 + i * 64; \
      sreg[i] = *(const int4*)(Kb + (size_t)(th_ * 256 + r_) * 256 + kk_ * 64 + sc0); \
    } } while (0)

#define LOADV(s_) do { \
    _Pragma("unroll") \
    for (int i = 0; i < 4; i++) { \
      int r_ = sr0 + i * 64; \
      sreg[i] = *(const int4*)(VTb + (size_t)r_ * 512 + (s_) * 64 + sc0); \
    } } while (0)

#define WRITES() do { \
    _Pragma("unroll") \
    for (int i = 0; i < 4; i++) { \
      int r_ = sr0 + i * 64; \
      *(int4*)(stageU + r_ * 72 + sc0) = sreg[i]; \
    } } while (0)

  // ---- phase 1: S = Q @ K^T, 8 fat stages, T14 prefetch ----
  LOADK(0);
#pragma unroll 1
  for (int s = 0; s < 8; s++) {
    __syncthreads();
    WRITES();
    if (s < 7) LOADK(s + 1);
    __syncthreads();
    const int th = s >> 2, kk2 = (s & 3) * 2;
#pragma unroll
    for (int ks = 0; ks < 2; ks++) {
#pragma unroll
      for (int ti = 0; ti < 4; ti++) {
        short8v bf = *(const short8v*)(stageU + (wt * 64 + ti * 16 + l16) * 72 + ks * 32 + lhi * 8);
        acc[0][th * 4 + ti] = MFMA16(a[0][kk2 + ks], bf, acc[0][th * 4 + ti]);
        acc[1][th * 4 + ti] = MFMA16(a[1][kk2 + ks], bf, acc[1][th * 4 + ti]);
      }
    }
  }

  // prefetch VT stage 0 — latency hides under softmax
  LOADV(0);

  // ---- softmax (exact, full T=512 per row) ----
#pragma unroll
  for (int mi = 0; mi < 2; mi++)
#pragma unroll
    for (int tj = 0; tj < 8; tj++)
#pragma unroll
      for (int i = 0; i < 4; i++) acc[mi][tj][i] *= SCALE;

  float mrow[2][4];
#pragma unroll
  for (int mi = 0; mi < 2; mi++)
#pragma unroll
    for (int i = 0; i < 4; i++) {
      float m = acc[mi][0][i];
#pragma unroll
      for (int tj = 1; tj < 8; tj++) m = fmaxf(m, acc[mi][tj][i]);
      m = fmaxf(m, __shfl_xor(m, 1));
      m = fmaxf(m, __shfl_xor(m, 2));
      m = fmaxf(m, __shfl_xor(m, 4));
      m = fmaxf(m, __shfl_xor(m, 8));
      mrow[mi][i] = m;
    }
  __syncthreads();   // phase-1 LDS reads done before red overlay is written
  if (l16 == 0) {
#pragma unroll
    for (int mi = 0; mi < 2; mi++)
#pragma unroll
      for (int i = 0; i < 4; i++)
        red[wave * 32 + mi * 16 + lhi * 4 + i] = mrow[mi][i];
  }
  __syncthreads();
#pragma unroll
  for (int mi = 0; mi < 2; mi++)
#pragma unroll
    for (int i = 0; i < 4; i++) {
      int rl = mi * 16 + lhi * 4 + i;
      int g = wq * 4;
      mrow[mi][i] = fmaxf(fmaxf(red[(g + 0) * 32 + rl], red[(g + 1) * 32 + rl]),
                          fmaxf(red[(g + 2) * 32 + rl], red[(g + 3) * 32 + rl]));
    }
  float srow[2][4];
#pragma unroll
  for (int mi = 0; mi < 2; mi++)
#pragma unroll
    for (int i = 0; i < 4; i++) {
      float s = 0.f;
#pragma unroll
      for (int tj = 0; tj < 8; tj++) {
        float p = __expf(acc[mi][tj][i] - mrow[mi][i]);
        acc[mi][tj][i] = p;
        s += p;
      }
      s += __shfl_xor(s, 1); s += __shfl_xor(s, 2);
      s += __shfl_xor(s, 4); s += __shfl_xor(s, 8);
      srow[mi][i] = s;
    }
  if (l16 == 0) {
#pragma unroll
    for (int mi = 0; mi < 2; mi++)
#pragma unroll
      for (int i = 0; i < 4; i++)
        red[256 + wave * 32 + mi * 16 + lhi * 4 + i] = srow[mi][i];
  }
  __syncthreads();
  float inv[2][4];
#pragma unroll
  for (int mi = 0; mi < 2; mi++)
#pragma unroll
    for (int i = 0; i < 4; i++) {
      int rl = mi * 16 + lhi * 4 + i;
      int g = wq * 4;
      float l = red[256 + (g + 0) * 32 + rl] + red[256 + (g + 1) * 32 + rl] +
                red[256 + (g + 2) * 32 + rl] + red[256 + (g + 3) * 32 + rl];
      inv[mi][i] = 1.0f / l;
    }
  __syncthreads();   // red reads done before P overwrites the overlay

  // ---- write P to Plds (bf16, padded rows) ----
#pragma unroll
  for (int mi = 0; mi < 2; mi++)
#pragma unroll
    for (int tj = 0; tj < 8; tj++)
#pragma unroll
      for (int i = 0; i < 4; i++) {
        int r = wq * 32 + mi * 16 + lhi * 4 + i;
        int t = (tj >> 2) * 256 + wt * 64 + (tj & 3) * 16 + l16;
        Plds[r * 520 + t] = f2bf(acc[mi][tj][i] * inv[mi][i]);
      }
  __syncthreads();   // Plds complete (all waves); phase-1 stage reads long done

  // ---- phase 3 stage 0 write + prefetch 1, then PT global write overlaps ----
  WRITES();          // VT stage 0
  LOADV(1);

  // PT[b][t][n0..n0+63], t = tid
  {
    unsigned short* PTb = PTg + (size_t)b * 512 * 4096;
    const int t = tid;
#pragma unroll
    for (int j = 0; j < 8; j++) {
      unsigned short tmp[8];
#pragma unroll
      for (int k = 0; k < 8; k++) tmp[k] = Plds[(j * 8 + k) * 520 + t];
      *(int4*)(PTb + (size_t)t * 4096 + n0 + j * 8) = *(int4*)tmp;
    }
  }

  // ---- phase 3: O = P @ V via VT rows, 8 fat stages ----
  float4v oacc[2][4];
#pragma unroll
  for (int mi = 0; mi < 2; mi++)
#pragma unroll
    for (int ci = 0; ci < 4; ci++) oacc[mi][ci] = (float4v)0.f;

#pragma unroll 1
  for (int s = 0; s < 8; s++) {
    if (s > 0) {
      __syncthreads();
      WRITES();
      if (s < 7) LOADV(s + 1);
    }
    __syncthreads();
#pragma unroll
    for (int ks = 0; ks < 2; ks++) {
      short8v pa0 = *(const short8v*)(Plds + (wq * 32 + l16) * 520 + s * 64 + ks * 32 + lhi * 8);
      short8v pa1 = *(const short8v*)(Plds + (wq * 32 + 16 + l16) * 520 + s * 64 + ks * 32 + lhi * 8);
#pragma unroll
      for (int ci = 0; ci < 4; ci++) {
        short8v bf = *(const short8v*)(stageU + (wt * 64 + ci * 16 + l16) * 72 + ks * 32 + lhi * 8);
        oacc[0][ci] = MFMA16(pa0, bf, oacc[0][ci]);
        oacc[1][ci] = MFMA16(pa1, bf, oacc[1][ci]);
      }
    }
  }
  __syncthreads();   // Plds reads done before Olds overlay

  // ---- epilogue: Olds [64][260] f32, add F_s, write out0 [b][c][n] ----
#pragma unroll
  for (int mi = 0; mi < 2; mi++)
#pragma unroll
    for (int ci = 0; ci < 4; ci++)
#pragma unroll
      for (int i = 0; i < 4; i++)
        Olds[(wq * 32 + mi * 16 + lhi * 4 + i) * 260 + wt * 64 + ci * 16 + l16] = oacc[mi][ci][i];
  __syncthreads();
  const float* Fsb = Fs + (size_t)b * 256 * 4096;
  float* o0 = out0 + (size_t)b * 256 * 4096;
  const int c = tid >> 1, nh = (tid & 1) * 32;
#pragma unroll
  for (int j8 = 0; j8 < 8; j8++) {
    float4 f = *(const float4*)&Fsb[(size_t)c * 4096 + n0 + nh + j8 * 4];
    float4 o;
    o.x = Olds[(nh + j8 * 4 + 0) * 260 + c] + f.x;
    o.y = Olds[(nh + j8 * 4 + 1) * 260 + c] + f.y;
    o.z = Olds[(nh + j8 * 4 + 2) * 260 + c] + f.z;
    o.w = Olds[(nh + j8 * 4 + 3) * 260 + c] + f.w;
    *(float4*)&o0[(size_t)c * 4096 + n0 + nh + j8 * 4] = o;
  }
#undef LOADK
#undef LOADV
#undef WRITES
}

// ---------- F_t_updated = PT @ Q  (B from QT), split-K=4, atomic (unchanged) ----------
__global__ __launch_bounds__(256) void k_ptq(
    const unsigned short* __restrict__ PTg, const unsigned short* __restrict__ QTg,
    float* __restrict__ out1) {
  __shared__ unsigned short As[64 * 72];
  __shared__ unsigned short Bs[64 * 72];
  const int tid = threadIdx.x;
  const int wave = tid >> 6, lane = tid & 63;
  const int l16 = lane & 15, lhi = lane >> 4;
  const int t0 = blockIdx.x * 64, c0 = blockIdx.y * 64;
  const int b = blockIdx.z >> 2, ksl = blockIdx.z & 3;
  const unsigned short* PTb = PTg + (size_t)b * 512 * 4096 + ksl * 1024;
  const unsigned short* QTb = QTg + (size_t)b * 256 * 4096 + ksl * 1024;
  const int wr = wave >> 1, wc = wave & 1;

  float4v acc[2][2];
#pragma unroll
  for (int mi = 0; mi < 2; mi++)
#pragma unroll
    for (int ni = 0; ni < 2; ni++) acc[mi][ni] = (float4v)0.f;

#pragma unroll 1
  for (int kk = 0; kk < 16; kk++) {
    __syncthreads();
#pragma unroll
    for (int i = 0; i < 2; i++) {
      int chunk = tid + i * 256;
      int row = chunk >> 3, col = (chunk & 7) * 8;
      *(int4*)(As + row * 72 + col) =
          *(const int4*)(PTb + (size_t)(t0 + row) * 4096 + kk * 64 + col);
      *(int4*)(Bs + row * 72 + col) =
          *(const int4*)(QTb + (size_t)(c0 + row) * 4096 + kk * 64 + col);
    }
    __syncthreads();
#pragma unroll
    for (int ks = 0; ks < 2; ks++) {
      short8v a0 = *(const short8v*)(As + (wr * 32 + l16) * 72 + ks * 32 + lhi * 8);
      short8v a1 = *(const short8v*)(As + (wr * 32 + 16 + l16) * 72 + ks * 32 + lhi * 8);
      short8v b0 = *(const short8v*)(Bs + (wc * 32 + l16) * 72 + ks * 32 + lhi * 8);
      short8v b1 = *(const short8v*)(Bs + (wc * 32 + 16 + l16) * 72 + ks * 32 + lhi * 8);
      acc[0][0] = MFMA16(a0, b0, acc[0][0]);
      acc[0][1] = MFMA16(a0, b1, acc[0][1]);
      acc[1][0] = MFMA16(a1, b0, acc[1][0]);
      acc[1][1] = MFMA16(a1, b1, acc[1][1]);
    }
  }
#pragma unroll
  for (int mi = 0; mi < 2; mi++)
#pragma unroll
    for (int ni = 0; ni < 2; ni++)
#pragma unroll
      for (int i = 0; i < 4; i++) {
        int t = t0 + wr * 32 + mi * 16 + lhi * 4 + i;
        int c = c0 + wc * 32 + ni * 16 + l16;
        atomicAdd(&out1[(size_t)(b * 512 + t) * 256 + c], acc[mi][ni][i]);
      }
}

extern "C" void kernel_launch(void* const* d_in, const int* in_sizes, int n_in,
                              void* d_out, int out_size, void* d_ws, size_t ws_size,
                              hipStream_t stream) {
  const float* Fs = (const float*)d_in[0];   // [8][256][4096]
  const float* Ft = (const float*)d_in[1];   // [8][512][256]
  float* out0 = (float*)d_out;               // [8][256][4096]
  float* out1 = out0 + (size_t)8 * 256 * 4096;  // [8][512][256]

  unsigned short* ws = (unsigned short*)d_ws;
  unsigned short* Q  = ws;               // [8][4096][256]
  unsigned short* QT = Q + 8388608;      // [8][256][4096]
  unsigned short* K  = QT + 8388608;     // [8][512][256]
  unsigned short* VT = K + 1048576;      // [8][256][512]
  unsigned short* PT = VT + 1048576;     // [8][512][4096]

  hipMemsetAsync(out1, 0, (size_t)1048576 * sizeof(float), stream);
  k_cast_transpose<<<dim3(128, 8, 8), 256, 0, stream>>>(Fs, QT, Q, 256, 4096);
  k_cast_transpose<<<dim3(8, 16, 8), 256, 0, stream>>>(Ft, K, VT, 512, 256);
  k_attn<<<dim3(64, 8), 512, 0, stream>>>(Q, K, VT, Fs, out0, PT);
  k_ptq<<<dim3(8, 4, 32), 256, 0, stream>>>(PT, QT, out1);
}

// Round 5
// 148.956 us; speedup vs baseline: 1.9506x; 1.9506x over previous
//
#include <hip/hip_runtime.h>
#include <hip/hip_bf16.h>
#include <stdint.h>

// B=8, C=256, H=W=64 (N=4096), T=512
// out0 = F_s + (softmax(Fs_t @ Ft^T / sqrt(T)) @ Ft) in [B][C][N] layout, fp32
// out1 = P^T @ Fs_t   [B][T][C] fp32

typedef __attribute__((ext_vector_type(8))) short short8v;   // 8 bf16
typedef __attribute__((ext_vector_type(4))) float float4v;

#define MFMA16(a, b, c) __builtin_amdgcn_mfma_f32_16x16x32_bf16(a, b, c, 0, 0, 0)
#define SCALE 0.04419417382415922f  // 1/sqrt(512)

static __device__ __forceinline__ unsigned short f2bf(float f) {
  union { float f; uint32_t u; } v; v.f = f;
  uint32_t r = v.u + 0x7fffu + ((v.u >> 16) & 1u);   // RNE
  return (unsigned short)(r >> 16);
}

// ---------- cast + transpose (unchanged) ----------
__global__ __launch_bounds__(256) void k_cast_transpose(
    const float* __restrict__ src, unsigned short* __restrict__ dstC,
    unsigned short* __restrict__ dstT, int R, int Cd) {
  __shared__ unsigned short tile[32][33];
  const size_t zoff = (size_t)blockIdx.z * R * Cd;
  const float* s = src + zoff;
  unsigned short* dc = dstC + zoff;
  unsigned short* dt = dstT + zoff;
  const int c0 = blockIdx.x * 32, r0 = blockIdx.y * 32;
  const int tid = threadIdx.x;
  const int r = tid >> 3, c4 = (tid & 7) * 4;

  float4 v = *(const float4*)&s[(size_t)(r0 + r) * Cd + c0 + c4];
  ushort4 bq;
  bq.x = f2bf(v.x); bq.y = f2bf(v.y); bq.z = f2bf(v.z); bq.w = f2bf(v.w);
  *(ushort4*)&dc[(size_t)(r0 + r) * Cd + c0 + c4] = bq;
  tile[r][c4 + 0] = bq.x; tile[r][c4 + 1] = bq.y;
  tile[r][c4 + 2] = bq.z; tile[r][c4 + 3] = bq.w;
  __syncthreads();
  ushort4 o;
  o.x = tile[c4 + 0][r]; o.y = tile[c4 + 1][r];
  o.z = tile[c4 + 2][r]; o.w = tile[c4 + 3][r];
  *(ushort4*)&dt[(size_t)(c0 + r) * R + r0 + c4] = o;
}

// ---------- fused attention: QBLK=64, 8 waves, T14 prefetch, fat stages ----------
// grid (64 n-blocks, 8 batches), 512 threads.
// LDS: [0,36864) stage [256][72] bf16 (K then VT chunks)
//      [36864,103424) Plds [64][520] bf16  (overlaid: red f32 early; Olds f32[64][260] late)
// NOTE: phase-1 stage loop is FULLY UNROLLED so every register-array index
// (acc[mi][th*4+ti], a[mi][kk2+ks]) is a compile-time constant — rule #20:
// runtime-indexed ext_vector arrays demote to scratch (round-4 regression:
// VGPR=88, WRITE_SIZE 559MB of spill traffic, 3x slowdown).
__global__ __launch_bounds__(512, 2) void k_attn(
    const unsigned short* __restrict__ Qg, const unsigned short* __restrict__ Kg,
    const unsigned short* __restrict__ VTg, const float* __restrict__ Fs,
    float* __restrict__ out0, unsigned short* __restrict__ PTg) {
  __shared__ char smem[103424];
  unsigned short* stageU = (unsigned short*)smem;          // [256][72]
  unsigned short* Plds = (unsigned short*)(smem + 36864);  // [64][520]
  float* red = (float*)(smem + 36864);                     // overlay
  float* Olds = (float*)(smem + 36864);                    // [64][260] overlay

  const int tid = threadIdx.x;
  const int wave = tid >> 6, lane = tid & 63;
  const int l16 = lane & 15, lhi = lane >> 4;
  const int wq = wave >> 2, wt = wave & 3;   // q-half, t/c-quarter
  const int b = blockIdx.y, n0 = blockIdx.x * 64;

  const unsigned short* Qb = Qg + (size_t)b * 4096 * 256;
  const unsigned short* Kb = Kg + (size_t)b * 512 * 256;
  const unsigned short* VTb = VTg + (size_t)b * 256 * 512;

  const int sr0 = tid >> 3;
  const int sc0 = (tid & 7) * 8;

  // ---- Q fragments in registers ----
  short8v a[2][8];
#pragma unroll
  for (int mi = 0; mi < 2; mi++)
#pragma unroll
    for (int kk = 0; kk < 8; kk++)
      a[mi][kk] = *(const short8v*)(Qb + (size_t)(n0 + wq * 32 + mi * 16 + l16) * 256 + kk * 32 + lhi * 8);

  float4v acc[2][8];
#pragma unroll
  for (int mi = 0; mi < 2; mi++)
#pragma unroll
    for (int tj = 0; tj < 8; tj++) acc[mi][tj] = (float4v)0.f;

  int4 sreg[4];

#define LOADK(s_) do { \
    const int th_ = (s_) >> 2, kk_ = (s_) & 3; \
    _Pragma("unroll") \
    for (int i = 0; i < 4; i++) { \
      int r_ = sr0 + i * 64; \
      sreg[i] = *(const int4*)(Kb + (size_t)(th_ * 256 + r_) * 256 + kk_ * 64 + sc0); \
    } } while (0)

#define LOADV(s_) do { \
    _Pragma("unroll") \
    for (int i = 0; i < 4; i++) { \
      int r_ = sr0 + i * 64; \
      sreg[i] = *(const int4*)(VTb + (size_t)r_ * 512 + (s_) * 64 + sc0); \
    } } while (0)

#define WRITES() do { \
    _Pragma("unroll") \
    for (int i = 0; i < 4; i++) { \
      int r_ = sr0 + i * 64; \
      *(int4*)(stageU + r_ * 72 + sc0) = sreg[i]; \
    } } while (0)

  // ---- phase 1: S = Q @ K^T, 8 fat stages, FULLY UNROLLED (static reg indices) ----
  LOADK(0);
#pragma unroll
  for (int s = 0; s < 8; s++) {
    __syncthreads();
    WRITES();
    if (s < 7) LOADK(s + 1);
    __syncthreads();
    const int th = s >> 2, kk2 = (s & 3) * 2;   // compile-time after unroll
#pragma unroll
    for (int ks = 0; ks < 2; ks++) {
#pragma unroll
      for (int ti = 0; ti < 4; ti++) {
        short8v bf = *(const short8v*)(stageU + (wt * 64 + ti * 16 + l16) * 72 + ks * 32 + lhi * 8);
        acc[0][th * 4 + ti] = MFMA16(a[0][kk2 + ks], bf, acc[0][th * 4 + ti]);
        acc[1][th * 4 + ti] = MFMA16(a[1][kk2 + ks], bf, acc[1][th * 4 + ti]);
      }
    }
  }

  // prefetch VT stage 0 — latency hides under softmax
  LOADV(0);

  // ---- softmax (exact, full T=512 per row) ----
#pragma unroll
  for (int mi = 0; mi < 2; mi++)
#pragma unroll
    for (int tj = 0; tj < 8; tj++)
#pragma unroll
      for (int i = 0; i < 4; i++) acc[mi][tj][i] *= SCALE;

  float mrow[2][4];
#pragma unroll
  for (int mi = 0; mi < 2; mi++)
#pragma unroll
    for (int i = 0; i < 4; i++) {
      float m = acc[mi][0][i];
#pragma unroll
      for (int tj = 1; tj < 8; tj++) m = fmaxf(m, acc[mi][tj][i]);
      m = fmaxf(m, __shfl_xor(m, 1));
      m = fmaxf(m, __shfl_xor(m, 2));
      m = fmaxf(m, __shfl_xor(m, 4));
      m = fmaxf(m, __shfl_xor(m, 8));
      mrow[mi][i] = m;
    }
  __syncthreads();   // phase-1 LDS reads done before red overlay write
  if (l16 == 0) {
#pragma unroll
    for (int mi = 0; mi < 2; mi++)
#pragma unroll
      for (int i = 0; i < 4; i++)
        red[wave * 32 + mi * 16 + lhi * 4 + i] = mrow[mi][i];
  }
  __syncthreads();
#pragma unroll
  for (int mi = 0; mi < 2; mi++)
#pragma unroll
    for (int i = 0; i < 4; i++) {
      int rl = mi * 16 + lhi * 4 + i;
      int g = wq * 4;
      mrow[mi][i] = fmaxf(fmaxf(red[(g + 0) * 32 + rl], red[(g + 1) * 32 + rl]),
                          fmaxf(red[(g + 2) * 32 + rl], red[(g + 3) * 32 + rl]));
    }
  float srow[2][4];
#pragma unroll
  for (int mi = 0; mi < 2; mi++)
#pragma unroll
    for (int i = 0; i < 4; i++) {
      float s = 0.f;
#pragma unroll
      for (int tj = 0; tj < 8; tj++) {
        float p = __expf(acc[mi][tj][i] - mrow[mi][i]);
        acc[mi][tj][i] = p;
        s += p;
      }
      s += __shfl_xor(s, 1); s += __shfl_xor(s, 2);
      s += __shfl_xor(s, 4); s += __shfl_xor(s, 8);
      srow[mi][i] = s;
    }
  if (l16 == 0) {
#pragma unroll
    for (int mi = 0; mi < 2; mi++)
#pragma unroll
      for (int i = 0; i < 4; i++)
        red[256 + wave * 32 + mi * 16 + lhi * 4 + i] = srow[mi][i];
  }
  __syncthreads();
  float inv[2][4];
#pragma unroll
  for (int mi = 0; mi < 2; mi++)
#pragma unroll
    for (int i = 0; i < 4; i++) {
      int rl = mi * 16 + lhi * 4 + i;
      int g = wq * 4;
      float l = red[256 + (g + 0) * 32 + rl] + red[256 + (g + 1) * 32 + rl] +
                red[256 + (g + 2) * 32 + rl] + red[256 + (g + 3) * 32 + rl];
      inv[mi][i] = 1.0f / l;
    }
  __syncthreads();   // red reads done before P overwrites the overlay

  // ---- write P to Plds (bf16, padded rows) ----
#pragma unroll
  for (int mi = 0; mi < 2; mi++)
#pragma unroll
    for (int tj = 0; tj < 8; tj++)
#pragma unroll
      for (int i = 0; i < 4; i++) {
        int r = wq * 32 + mi * 16 + lhi * 4 + i;
        int t = (tj >> 2) * 256 + wt * 64 + (tj & 3) * 16 + l16;
        Plds[r * 520 + t] = f2bf(acc[mi][tj][i] * inv[mi][i]);
      }
  __syncthreads();   // Plds complete (all waves)

  // ---- VT stage 0 write + prefetch 1; PT global write overlaps the load ----
  WRITES();          // VT stage 0 into stageU
  LOADV(1);

  // PT[b][t][n0..n0+63], t = tid
  {
    unsigned short* PTb = PTg + (size_t)b * 512 * 4096;
    const int t = tid;
#pragma unroll
    for (int j = 0; j < 8; j++) {
      unsigned short tmp[8];
#pragma unroll
      for (int k = 0; k < 8; k++) tmp[k] = Plds[(j * 8 + k) * 520 + t];
      *(int4*)(PTb + (size_t)t * 4096 + n0 + j * 8) = *(int4*)tmp;
    }
  }
  __syncthreads();   // FENCE: stage-0 WRITES visible to all waves before s=0 reads
                     // (round-4 latent race fixed)

  // ---- phase 3: O = P @ V via VT rows, 8 fat stages ----
  float4v oacc[2][4];
#pragma unroll
  for (int mi = 0; mi < 2; mi++)
#pragma unroll
    for (int ci = 0; ci < 4; ci++) oacc[mi][ci] = (float4v)0.f;

#pragma unroll 1
  for (int s = 0; s < 8; s++) {
    if (s > 0) {
      __syncthreads();
      WRITES();
      if (s < 7) LOADV(s + 1);
      __syncthreads();
    }
#pragma unroll
    for (int ks = 0; ks < 2; ks++) {
      short8v pa0 = *(const short8v*)(Plds + (wq * 32 + l16) * 520 + s * 64 + ks * 32 + lhi * 8);
      short8v pa1 = *(const short8v*)(Plds + (wq * 32 + 16 + l16) * 520 + s * 64 + ks * 32 + lhi * 8);
#pragma unroll
      for (int ci = 0; ci < 4; ci++) {
        short8v bf = *(const short8v*)(stageU + (wt * 64 + ci * 16 + l16) * 72 + ks * 32 + lhi * 8);
        oacc[0][ci] = MFMA16(pa0, bf, oacc[0][ci]);
        oacc[1][ci] = MFMA16(pa1, bf, oacc[1][ci]);
      }
    }
  }
  __syncthreads();   // Plds reads done before Olds overlay

  // ---- epilogue: Olds [64][260] f32, add F_s, write out0 [b][c][n] ----
#pragma unroll
  for (int mi = 0; mi < 2; mi++)
#pragma unroll
    for (int ci = 0; ci < 4; ci++)
#pragma unroll
      for (int i = 0; i < 4; i++)
        Olds[(wq * 32 + mi * 16 + lhi * 4 + i) * 260 + wt * 64 + ci * 16 + l16] = oacc[mi][ci][i];
  __syncthreads();
  const float* Fsb = Fs + (size_t)b * 256 * 4096;
  float* o0 = out0 + (size_t)b * 256 * 4096;
  const int c = tid >> 1, nh = (tid & 1) * 32;
#pragma unroll
  for (int j8 = 0; j8 < 8; j8++) {
    float4 f = *(const float4*)&Fsb[(size_t)c * 4096 + n0 + nh + j8 * 4];
    float4 o;
    o.x = Olds[(nh + j8 * 4 + 0) * 260 + c] + f.x;
    o.y = Olds[(nh + j8 * 4 + 1) * 260 + c] + f.y;
    o.z = Olds[(nh + j8 * 4 + 2) * 260 + c] + f.z;
    o.w = Olds[(nh + j8 * 4 + 3) * 260 + c] + f.w;
    *(float4*)&o0[(size_t)c * 4096 + n0 + nh + j8 * 4] = o;
  }
#undef LOADK
#undef LOADV
#undef WRITES
}

// ---------- F_t_updated = PT @ Q  (B from QT), split-K=4, atomic (unchanged) ----------
__global__ __launch_bounds__(256) void k_ptq(
    const unsigned short* __restrict__ PTg, const unsigned short* __restrict__ QTg,
    float* __restrict__ out1) {
  __shared__ unsigned short As[64 * 72];
  __shared__ unsigned short Bs[64 * 72];
  const int tid = threadIdx.x;
  const int wave = tid >> 6, lane = tid & 63;
  const int l16 = lane & 15, lhi = lane >> 4;
  const int t0 = blockIdx.x * 64, c0 = blockIdx.y * 64;
  const int b = blockIdx.z >> 2, ksl = blockIdx.z & 3;
  const unsigned short* PTb = PTg + (size_t)b * 512 * 4096 + ksl * 1024;
  const unsigned short* QTb = QTg + (size_t)b * 256 * 4096 + ksl * 1024;
  const int wr = wave >> 1, wc = wave & 1;

  float4v acc[2][2];
#pragma unroll
  for (int mi = 0; mi < 2; mi++)
#pragma unroll
    for (int ni = 0; ni < 2; ni++) acc[mi][ni] = (float4v)0.f;

#pragma unroll 1
  for (int kk = 0; kk < 16; kk++) {
    __syncthreads();
#pragma unroll
    for (int i = 0; i < 2; i++) {
      int chunk = tid + i * 256;
      int row = chunk >> 3, col = (chunk & 7) * 8;
      *(int4*)(As + row * 72 + col) =
          *(const int4*)(PTb + (size_t)(t0 + row) * 4096 + kk * 64 + col);
      *(int4*)(Bs + row * 72 + col) =
          *(const int4*)(QTb + (size_t)(c0 + row) * 4096 + kk * 64 + col);
    }
    __syncthreads();
#pragma unroll
    for (int ks = 0; ks < 2; ks++) {
      short8v a0 = *(const short8v*)(As + (wr * 32 + l16) * 72 + ks * 32 + lhi * 8);
      short8v a1 = *(const short8v*)(As + (wr * 32 + 16 + l16) * 72 + ks * 32 + lhi * 8);
      short8v b0 = *(const short8v*)(Bs + (wc * 32 + l16) * 72 + ks * 32 + lhi * 8);
      short8v b1 = *(const short8v*)(Bs + (wc * 32 + 16 + l16) * 72 + ks * 32 + lhi * 8);
      acc[0][0] = MFMA16(a0, b0, acc[0][0]);
      acc[0][1] = MFMA16(a0, b1, acc[0][1]);
      acc[1][0] = MFMA16(a1, b0, acc[1][0]);
      acc[1][1] = MFMA16(a1, b1, acc[1][1]);
    }
  }
#pragma unroll
  for (int mi = 0; mi < 2; mi++)
#pragma unroll
    for (int ni = 0; ni < 2; ni++)
#pragma unroll
      for (int i = 0; i < 4; i++) {
        int t = t0 + wr * 32 + mi * 16 + lhi * 4 + i;
        int c = c0 + wc * 32 + ni * 16 + l16;
        atomicAdd(&out1[(size_t)(b * 512 + t) * 256 + c], acc[mi][ni][i]);
      }
}

extern "C" void kernel_launch(void* const* d_in, const int* in_sizes, int n_in,
                              void* d_out, int out_size, void* d_ws, size_t ws_size,
                              hipStream_t stream) {
  const float* Fs = (const float*)d_in[0];   // [8][256][4096]
  const float* Ft = (const float*)d_in[1];   // [8][512][256]
  float* out0 = (float*)d_out;               // [8][256][4096]
  float* out1 = out0 + (size_t)8 * 256 * 4096;  // [8][512][256]

  unsigned short* ws = (unsigned short*)d_ws;
  unsigned short* Q  = ws;               // [8][4096][256]
  unsigned short* QT = Q + 8388608;      // [8][256][4096]
  unsigned short* K  = QT + 8388608;     // [8][512][256]
  unsigned short* VT = K + 1048576;      // [8][256][512]
  unsigned short* PT = VT + 1048576;     // [8][512][4096]

  hipMemsetAsync(out1, 0, (size_t)1048576 * sizeof(float), stream);
  k_cast_transpose<<<dim3(128, 8, 8), 256, 0, stream>>>(Fs, QT, Q, 256, 4096);
  k_cast_transpose<<<dim3(8, 16, 8), 256, 0, stream>>>(Ft, K, VT, 512, 256);
  k_attn<<<dim3(64, 8), 512, 0, stream>>>(Q, K, VT, Fs, out0, PT);
  k_ptq<<<dim3(8, 4, 32), 256, 0, stream>>>(PT, QT, out1);
}